// Round 1
// baseline (199.946 us; speedup 1.0000x reference)
//
#include <hip/hip_runtime.h>
#include <hip/hip_bf16.h>
#include <math.h>

// Problem: IntraSampleNTXEntLoss  S=4, V=2, B=8192, D=512, T=0.1
// views: (S,V,B,D) fp32, flat index ((s*V+v)*B + b)*D + d
// Output: scalar mean loss.
//
// Strategy: one 64-lane wave per batch element b. Each lane holds 8 elems of
// each of the 8 vectors (2x float4 coalesced loads per vector). Compute the
// 4x8 anchor Gram block + 4 odd self-dots as per-lane partials, butterfly
// shfl_xor reduce (6 steps, wave=64), then every lane redundantly evaluates
// the 4 anchor losses (7 finite logits each; masked -inf entries never
// materialized). Block partial -> deterministic single-block reduction.

#define NS 4
#define NV 2
#define NB 8192
#define ND 512
#define T_INV 10.0f
#define WAVES_PER_BLOCK 4
#define NBLOCKS (NB / WAVES_PER_BLOCK)

__device__ __forceinline__ float dot8(const float4& a0, const float4& a1,
                                      const float4& b0, const float4& b1) {
    return a0.x*b0.x + a0.y*b0.y + a0.z*b0.z + a0.w*b0.w +
           a1.x*b1.x + a1.y*b1.y + a1.z*b1.z + a1.w*b1.w;
}

__global__ __launch_bounds__(256) void ntxent_main(const float* __restrict__ views,
                                                   float* __restrict__ partial) {
    const int wave = threadIdx.x >> 6;
    const int lane = threadIdx.x & 63;
    const int b = blockIdx.x * WAVES_PER_BLOCK + wave;

    // Load the 4 anchor vectors (s, v=0) -> flat k = 2s
    float4 A[4][2];
#pragma unroll
    for (int a = 0; a < 4; ++a) {
        const float* p = views + ((size_t)(2 * a) * NB + b) * ND;
        A[a][0] = *(const float4*)(p + 4 * lane);
        A[a][1] = *(const float4*)(p + 256 + 4 * lane);
    }

    float g[4][8];   // anchor a (k=2a) dot vector k, per-lane partial
    float n1[4];     // self-dot of odd vectors k=2j+1, per-lane partial

#pragma unroll
    for (int k = 0; k < 8; ++k) {
        float4 c0, c1;
        if (k & 1) {
            const float* p = views + ((size_t)k * NB + b) * ND;
            c0 = *(const float4*)(p + 4 * lane);
            c1 = *(const float4*)(p + 256 + 4 * lane);
            n1[k >> 1] = dot8(c0, c1, c0, c1);
        } else {
            c0 = A[k >> 1][0];
            c1 = A[k >> 1][1];
        }
#pragma unroll
        for (int a = 0; a < 4; ++a) {
            g[a][k] = dot8(A[a][0], A[a][1], c0, c1);
        }
    }

    // Butterfly reduce all 36 partials across the 64-lane wave
#pragma unroll
    for (int m = 1; m < 64; m <<= 1) {
#pragma unroll
        for (int a = 0; a < 4; ++a) {
#pragma unroll
            for (int k = 0; k < 8; ++k) g[a][k] += __shfl_xor(g[a][k], m, 64);
        }
#pragma unroll
        for (int j = 0; j < 4; ++j) n1[j] += __shfl_xor(n1[j], m, 64);
    }

    // All lanes now hold full dots; compute the 4 anchor losses redundantly.
    float rn[8];
#pragma unroll
    for (int k = 0; k < 8; ++k) {
        float sd = (k & 1) ? n1[k >> 1] : g[k >> 1][k];  // self-dot
        rn[k] = 1.0f / fmaxf(sqrtf(sd), 1e-12f);
    }

    float loss = 0.0f;
#pragma unroll
    for (int a = 0; a < 4; ++a) {
        const float ia = rn[2 * a];
        const float l0 = T_INV * g[a][2 * a + 1] * ia * rn[2 * a + 1]; // sim_pos
        float lv[6];
        int c = 0;
        float mx = l0;
#pragma unroll
        for (int k = 0; k < 8; ++k) {
            if ((k >> 1) != a) {
                lv[c] = T_INV * g[a][k] * ia * rn[k];
                mx = fmaxf(mx, lv[c]);
                ++c;
            }
        }
        float se = __expf(l0 - mx);
#pragma unroll
        for (int i = 0; i < 6; ++i) se += __expf(lv[i] - mx);
        loss += mx + __logf(se) - l0;
    }

    // Block reduction: 4 waves -> one partial per block
    __shared__ float sm[WAVES_PER_BLOCK];
    if (lane == 0) sm[wave] = loss;
    __syncthreads();
    if (threadIdx.x == 0) {
        partial[blockIdx.x] = sm[0] + sm[1] + sm[2] + sm[3];
    }
}

__global__ __launch_bounds__(256) void ntxent_reduce(const float* __restrict__ partial,
                                                     float* __restrict__ out) {
    __shared__ double sm[256];
    double s = 0.0;
    for (int i = threadIdx.x; i < NBLOCKS; i += 256) s += (double)partial[i];
    sm[threadIdx.x] = s;
    __syncthreads();
    for (int off = 128; off > 0; off >>= 1) {
        if (threadIdx.x < off) sm[threadIdx.x] += sm[threadIdx.x + off];
        __syncthreads();
    }
    if (threadIdx.x == 0) out[0] = (float)(sm[0] / (double)(NS * NB));
}

extern "C" void kernel_launch(void* const* d_in, const int* in_sizes, int n_in,
                              void* d_out, int out_size, void* d_ws, size_t ws_size,
                              hipStream_t stream) {
    const float* views = (const float*)d_in[0];
    float* out = (float*)d_out;
    float* partial = (float*)d_ws;  // NBLOCKS floats = 8 KiB

    ntxent_main<<<NBLOCKS, 256, 0, stream>>>(views, partial);
    ntxent_reduce<<<1, 256, 0, stream>>>(partial, out);
}

// Round 2
// 197.185 us; speedup vs baseline: 1.0140x; 1.0140x over previous
//
#include <hip/hip_runtime.h>
#include <hip/hip_bf16.h>
#include <math.h>

// Problem: IntraSampleNTXEntLoss  S=4, V=2, B=8192, D=512, T=0.1
// views: (S,V,B,D) fp32, flat index ((s*V+v)*B + b)*D + d
// Output: scalar mean loss.
//
// R1: one 64-lane wave per batch element b (perfect float4 coalescing).
// 30 unique dots (even-even Gram is symmetric: 10, even-odd: 16, odd self: 4).
// Cross-lane reduction via DPP (row_shr 1/2/4/8 + row_bcast 15/31) -> pure
// VALU on each SIMD, zero LDS-pipe contention (R0 used 216 shfl_xor/wave =
// ~17us of serialized ds_swizzle per CU). Sum lands in lane 63; lane 63
// computes the 4 anchor losses (7 finite logits each; masked -inf entries
// never materialized). Block partial -> deterministic 1-block reduction.

#define NS 4
#define NB 8192
#define ND 512
#define T_INV 10.0f
#define WAVES_PER_BLOCK 4
#define NBLOCKS (NB / WAVES_PER_BLOCK)

__device__ __forceinline__ float dot8(const float4& a0, const float4& a1,
                                      const float4& b0, const float4& b1) {
    return a0.x*b0.x + a0.y*b0.y + a0.z*b0.z + a0.w*b0.w +
           a1.x*b1.x + a1.y*b1.y + a1.z*b1.z + a1.w*b1.w;
}

template <int CTRL, int RM>
__device__ __forceinline__ float dpp_add(float v, float x) {
    int xi = __builtin_bit_cast(int, x);
    int ri = __builtin_amdgcn_update_dpp(0, xi, CTRL, RM, 0xf, true);
    return v + __builtin_bit_cast(float, ri);
}

// Full 64-lane sum; result valid in lane 63. All DPP (VALU pipe only).
__device__ __forceinline__ float wave_sum63(float v) {
    v = dpp_add<0x111, 0xf>(v, v);  // row_shr:1
    v = dpp_add<0x112, 0xf>(v, v);  // row_shr:2
    v = dpp_add<0x114, 0xf>(v, v);  // row_shr:4
    v = dpp_add<0x118, 0xf>(v, v);  // row_shr:8  -> lane 15 of each row16 = row sum
    v = dpp_add<0x142, 0xa>(v, v);  // row_bcast:15 into rows 1,3
    v = dpp_add<0x143, 0xc>(v, v);  // row_bcast:31 into rows 2,3 -> lane 63 = total
    return v;
}

__global__ __launch_bounds__(256) void ntxent_main(const float* __restrict__ views,
                                                   float* __restrict__ partial) {
    const int wave = threadIdx.x >> 6;
    const int lane = threadIdx.x & 63;
    const int b = blockIdx.x * WAVES_PER_BLOCK + wave;
    const int off = 4 * lane;  // first float4; second at +256 floats

    // Load the 4 anchor vectors (s, v=0) -> flat row k = 2a
    float4 A[4][2];
#pragma unroll
    for (int a = 0; a < 4; ++a) {
        const float* p = views + ((size_t)(2 * a) * NB + b) * ND + off;
        A[a][0] = *(const float4*)p;
        A[a][1] = *(const float4*)(p + 256);
    }

    // even-even Gram, upper triangle incl. diagonal (10 unique)
    float ee[10];
    {
        int t = 0;
#pragma unroll
        for (int a = 0; a < 4; ++a)
#pragma unroll
            for (int a2 = a; a2 < 4; ++a2)
                ee[t++] = dot8(A[a][0], A[a][1], A[a2][0], A[a2][1]);
    }

    // stream the 4 odd vectors: anchor-dot (16) + self-dot (4)
    float eo[4][4], oo[4];
#pragma unroll
    for (int j = 0; j < 4; ++j) {
        const float* p = views + ((size_t)(2 * j + 1) * NB + b) * ND + off;
        float4 c0 = *(const float4*)p;
        float4 c1 = *(const float4*)(p + 256);
        oo[j] = dot8(c0, c1, c0, c1);
#pragma unroll
        for (int a = 0; a < 4; ++a) eo[a][j] = dot8(A[a][0], A[a][1], c0, c1);
    }

    // DPP-reduce all 30 partials; totals land in lane 63
#pragma unroll
    for (int i = 0; i < 10; ++i) ee[i] = wave_sum63(ee[i]);
#pragma unroll
    for (int a = 0; a < 4; ++a)
#pragma unroll
        for (int j = 0; j < 4; ++j) eo[a][j] = wave_sum63(eo[a][j]);
#pragma unroll
    for (int j = 0; j < 4; ++j) oo[j] = wave_sum63(oo[j]);

    __shared__ float sm[WAVES_PER_BLOCK];

    if (lane == 63) {
        // EE[a][a2] -> index into ee[] (symmetric)
        const int EE[4][4] = {{0,1,2,3},{1,4,5,6},{2,5,7,8},{3,6,8,9}};
        float rn[8];
#pragma unroll
        for (int a = 0; a < 4; ++a) {
            rn[2*a]     = 1.0f / fmaxf(sqrtf(ee[EE[a][a]]), 1e-12f);
            rn[2*a + 1] = 1.0f / fmaxf(sqrtf(oo[a]), 1e-12f);
        }
        float loss = 0.0f;
#pragma unroll
        for (int a = 0; a < 4; ++a) {
            const float ia = rn[2*a];
            const float l0 = T_INV * eo[a][a] * ia * rn[2*a + 1];  // sim_pos
            float lv[6];
            int c = 0;
            float mx = l0;
#pragma unroll
            for (int k = 0; k < 8; ++k) {
                if ((k >> 1) != a) {
                    float s = (k & 1) ? (eo[a][k >> 1] * ia * rn[k])
                                      : (ee[EE[a][k >> 1]] * ia * rn[k]);
                    lv[c] = T_INV * s;
                    mx = fmaxf(mx, lv[c]);
                    ++c;
                }
            }
            float se = __expf(l0 - mx);
#pragma unroll
            for (int i = 0; i < 6; ++i) se += __expf(lv[i] - mx);
            loss += mx + __logf(se) - l0;
        }
        sm[wave] = loss;
    }
    __syncthreads();
    if (threadIdx.x == 0) {
        partial[blockIdx.x] = sm[0] + sm[1] + sm[2] + sm[3];
    }
}

__global__ __launch_bounds__(256) void ntxent_reduce(const float* __restrict__ partial,
                                                     float* __restrict__ out) {
    __shared__ double sm[256];
    double s = 0.0;
    for (int i = threadIdx.x; i < NBLOCKS; i += 256) s += (double)partial[i];
    sm[threadIdx.x] = s;
    __syncthreads();
    for (int off = 128; off > 0; off >>= 1) {
        if (threadIdx.x < off) sm[threadIdx.x] += sm[threadIdx.x + off];
        __syncthreads();
    }
    if (threadIdx.x == 0) out[0] = (float)(sm[0] / (double)(NS * NB));
}

extern "C" void kernel_launch(void* const* d_in, const int* in_sizes, int n_in,
                              void* d_out, int out_size, void* d_ws, size_t ws_size,
                              hipStream_t stream) {
    const float* views = (const float*)d_in[0];
    float* out = (float*)d_out;
    float* partial = (float*)d_ws;  // NBLOCKS floats = 8 KiB

    ntxent_main<<<NBLOCKS, 256, 0, stream>>>(views, partial);
    ntxent_reduce<<<1, 256, 0, stream>>>(partial, out);
}

// Round 4
// 190.121 us; speedup vs baseline: 1.0517x; 1.0372x over previous
//
#include <hip/hip_runtime.h>
#include <hip/hip_bf16.h>
#include <math.h>

// Problem: IntraSampleNTXEntLoss  S=4, V=2, B=8192, D=512, T=0.1
// views: (S,V,B,D) fp32, flat index ((s*V+v)*B + b)*D + d
// Output: scalar mean loss.
//
// R3 (= R2 with compile fix): max memory-level parallelism. One 64-lane wave
// per batch element b. ALL 16 global_load_dwordx4 issued up front (8 vectors
// x 2 float4/lane, wave-uniform row bases), nontemporal (streamed once, via
// native ext_vector_type — HIP_vector_type rejected by the builtin). Then 30
// unique dots (even-even Gram symmetric: 10, even-odd: 16, odd self: 4),
// DPP-only wave reduction (row_shr 1/2/4/8 + row_bcast 15/31, pure VALU),
// lane 63 computes the 4 anchor losses (7 finite logits each; masked -inf
// never materialized) and stores one partial per wave. No LDS, no
// __syncthreads. Deterministic 1-block reduce kernel.

#define NS 4
#define NB 8192
#define ND 512
#define T_INV 10.0f
#define WAVES_PER_BLOCK 4
#define NBLOCKS (NB / WAVES_PER_BLOCK)
#define NPART NB  // one partial per wave (= per batch element)

typedef float fx4 __attribute__((ext_vector_type(4)));

__device__ __forceinline__ float dot8(const fx4& a0, const fx4& a1,
                                      const fx4& b0, const fx4& b1) {
    return a0.x*b0.x + a0.y*b0.y + a0.z*b0.z + a0.w*b0.w +
           a1.x*b1.x + a1.y*b1.y + a1.z*b1.z + a1.w*b1.w;
}

template <int CTRL, int RM>
__device__ __forceinline__ float dpp_add(float v, float x) {
    int xi = __builtin_bit_cast(int, x);
    int ri = __builtin_amdgcn_update_dpp(0, xi, CTRL, RM, 0xf, true);
    return v + __builtin_bit_cast(float, ri);
}

// Full 64-lane sum; result valid in lane 63. All DPP (VALU pipe only).
__device__ __forceinline__ float wave_sum63(float v) {
    v = dpp_add<0x111, 0xf>(v, v);  // row_shr:1
    v = dpp_add<0x112, 0xf>(v, v);  // row_shr:2
    v = dpp_add<0x114, 0xf>(v, v);  // row_shr:4
    v = dpp_add<0x118, 0xf>(v, v);  // row_shr:8  -> lane 15 of each row16
    v = dpp_add<0x142, 0xa>(v, v);  // row_bcast:15 into rows 1,3
    v = dpp_add<0x143, 0xc>(v, v);  // row_bcast:31 into rows 2,3 -> lane 63
    return v;
}

__global__ __launch_bounds__(256) void ntxent_main(const float* __restrict__ views,
                                                   float* __restrict__ partial) {
    const int wave = threadIdx.x >> 6;
    const int lane = threadIdx.x & 63;
    const int b = blockIdx.x * WAVES_PER_BLOCK + wave;
    const int off = 4 * lane;  // first float4; second at +256 floats

    // Phase 1: issue ALL 16 loads (8 rows x 2 float4); 16 in flight.
    fx4 V[8][2];
#pragma unroll
    for (int k = 0; k < 8; ++k) {
        const fx4* p = (const fx4*)(views + ((size_t)k * NB + b) * ND + off);
        V[k][0] = __builtin_nontemporal_load(p);
        V[k][1] = __builtin_nontemporal_load(p + 64);  // +256 floats
    }

    // Phase 2: 30 unique per-lane partial dots.
    float ee[10];  // even-even Gram upper triangle incl. diagonal
    {
        int t = 0;
#pragma unroll
        for (int a = 0; a < 4; ++a)
#pragma unroll
            for (int a2 = a; a2 < 4; ++a2)
                ee[t++] = dot8(V[2*a][0], V[2*a][1], V[2*a2][0], V[2*a2][1]);
    }
    float eo[4][4], oo[4];
#pragma unroll
    for (int j = 0; j < 4; ++j) {
        oo[j] = dot8(V[2*j+1][0], V[2*j+1][1], V[2*j+1][0], V[2*j+1][1]);
#pragma unroll
        for (int a = 0; a < 4; ++a)
            eo[a][j] = dot8(V[2*a][0], V[2*a][1], V[2*j+1][0], V[2*j+1][1]);
    }

    // Phase 3: DPP-reduce all 30 partials; totals land in lane 63.
#pragma unroll
    for (int i = 0; i < 10; ++i) ee[i] = wave_sum63(ee[i]);
#pragma unroll
    for (int a = 0; a < 4; ++a)
#pragma unroll
        for (int j = 0; j < 4; ++j) eo[a][j] = wave_sum63(eo[a][j]);
#pragma unroll
    for (int j = 0; j < 4; ++j) oo[j] = wave_sum63(oo[j]);

    // Phase 4: lane 63 computes the 4 anchor losses and stores the partial.
    if (lane == 63) {
        const int EE[4][4] = {{0,1,2,3},{1,4,5,6},{2,5,7,8},{3,6,8,9}};
        float rn[8];
#pragma unroll
        for (int a = 0; a < 4; ++a) {
            rn[2*a]     = 1.0f / fmaxf(sqrtf(ee[EE[a][a]]), 1e-12f);
            rn[2*a + 1] = 1.0f / fmaxf(sqrtf(oo[a]), 1e-12f);
        }
        float loss = 0.0f;
#pragma unroll
        for (int a = 0; a < 4; ++a) {
            const float ia = rn[2*a];
            const float l0 = T_INV * eo[a][a] * ia * rn[2*a + 1];  // sim_pos
            float lv[6];
            int c = 0;
            float mx = l0;
#pragma unroll
            for (int k = 0; k < 8; ++k) {
                if ((k >> 1) != a) {
                    float s = (k & 1) ? (eo[a][k >> 1] * ia * rn[k])
                                      : (ee[EE[a][k >> 1]] * ia * rn[k]);
                    lv[c] = T_INV * s;
                    mx = fmaxf(mx, lv[c]);
                    ++c;
                }
            }
            float se = __expf(l0 - mx);
#pragma unroll
            for (int i = 0; i < 6; ++i) se += __expf(lv[i] - mx);
            loss += mx + __logf(se) - l0;
        }
        partial[b] = loss;
    }
}

__global__ __launch_bounds__(256) void ntxent_reduce(const float* __restrict__ partial,
                                                     float* __restrict__ out) {
    __shared__ double sm[256];
    double s = 0.0;
    for (int i = threadIdx.x; i < NPART; i += 256) s += (double)partial[i];
    sm[threadIdx.x] = s;
    __syncthreads();
    for (int off = 128; off > 0; off >>= 1) {
        if (threadIdx.x < off) sm[threadIdx.x] += sm[threadIdx.x + off];
        __syncthreads();
    }
    if (threadIdx.x == 0) out[0] = (float)(sm[0] / (double)(NS * NB));
}

extern "C" void kernel_launch(void* const* d_in, const int* in_sizes, int n_in,
                              void* d_out, int out_size, void* d_ws, size_t ws_size,
                              hipStream_t stream) {
    const float* views = (const float*)d_in[0];
    float* out = (float*)d_out;
    float* partial = (float*)d_ws;  // NPART floats = 32 KiB of d_ws

    ntxent_main<<<NBLOCKS, 256, 0, stream>>>(views, partial);
    ntxent_reduce<<<1, 256, 0, stream>>>(partial, out);
}